// Round 12
// baseline (248.554 us; speedup 1.0000x reference)
//
#include <hip/hip_runtime.h>
#include <hip/hip_fp16.h>

// KnnExpansion: out[f, n] = sum_k alpha[i[n,k], f] * exp(-0.5 * d[n,k] / sigma^2)
// N=131072, K=32, M=65536, F=64.
//
// Proven (r10): fused in-register quartile partition + 4-phase L2-resident
// f16 gather, batched prologue = 53us main. r11 proved bytes are NOT the
// wall (i8 halved bytes, time rose) -> request-rate model. This round
// halves gather INSTRUCTIONS: one dword gather covers TWO rows (lanes 0-31
// row of entry 2t, lanes 32-63 entry 2t+1; 2 channels/lane). The packed
// entry comes from sortbuf LDS via per-half address (broadcast ds_read,
// conflict-free) -- no readlane pairs, no divergent select, no r9-style
// VGPR explosion. Cross-half shfl_xor(32) reduce in the epilogue.

#define N_Q    131072
#define K_NB   32
#define F_CH   64
#define M_ROWS 65536

// ---- pre-pass: alpha f32 -> f16 (streaming, ~3us) ----
__global__ __launch_bounds__(256) void cvt_alpha_f16(
    const float* __restrict__ alpha, __half* __restrict__ a16)
{
    const int t = blockIdx.x * 256 + threadIdx.x;
    const float4 v0 = ((const float4*)alpha)[(size_t)t * 2 + 0];
    const float4 v1 = ((const float4*)alpha)[(size_t)t * 2 + 1];
    union { __half2 h2[4]; uint4 u; } pk;
    pk.h2[0] = __floats2half2_rn(v0.x, v0.y);
    pk.h2[1] = __floats2half2_rn(v0.z, v0.w);
    pk.h2[2] = __floats2half2_rn(v1.x, v1.y);
    pk.h2[3] = __floats2half2_rn(v1.z, v1.w);
    ((uint4*)a16)[t] = pk.u;
}

// ---- fused main: batched prologue + quartile partition + paired gather ----
__global__ __launch_bounds__(512, 4) void knn_exp_pair(
    const float*  __restrict__ dmat,   // [N, 32]
    const int*    __restrict__ imat,   // [N, 32]
    const __half* __restrict__ a16,    // [65536, 64]
    const float*  __restrict__ sigma,  // [1]
    float*        __restrict__ out)    // [64, N]
{
    __shared__ float    tile[64][65];        // +1 pad
    __shared__ unsigned sortbuf[8][8][32];   // wave-local sort scratch

    const int lane   = threadIdx.x & 63;
    const int wave   = threadIdx.x >> 6;     // 8 waves x 8 queries
    const int n0     = blockIdx.x * 64;
    const bool hi    = (lane >= 32);
    const int  h     = lane >> 5;            // which row of the pair
    const int  lane31 = lane & 31;
    const unsigned lanebyte = (unsigned)lane31 * 4u;  // 2 channels x 2B

    const float s = sigma[0];
    const float c = -0.5f / (s * s);

    // ---- batched prologue: 8 stream loads issued back-to-back (r10) ----
    const int nbase = n0 + wave * 8;
    const char* pbase = hi
        ? (const char*)&imat[(size_t)nbase * K_NB + (lane - 32)]
        : (const char*)&dmat[(size_t)nbase * K_NB + lane];
    unsigned raw[8];
    #pragma unroll
    for (int qi = 0; qi < 8; ++qi)
        raw[qi] = __builtin_nontemporal_load(
            (const unsigned*)(pbase + (size_t)qi * (K_NB * 4)));

    __builtin_amdgcn_sched_barrier(0);   // keep the batch; no sinking

    // ---- in-register quartile partition, pack (idx<<16 | f16(w)) ----
    #pragma unroll
    for (int qi = 0; qi < 8; ++qi) {
        const float wv = __expf(c * __uint_as_float(raw[qi])); // valid on lo
        const int   iv = (int)raw[qi];                         // valid on hi

        const unsigned hbits = (unsigned)__half_as_ushort(__float2half_rn(wv));
        const unsigned hb    = (unsigned)__shfl((int)hbits, lane & 31);

        const int quart = (iv >> 14) & 3;
        const unsigned long long m0 = __ballot(hi && quart == 0);
        const unsigned long long m1 = __ballot(hi && quart == 1);
        const unsigned long long m2 = __ballot(hi && quart == 2);
        const unsigned long long m3 = __ballot(hi && quart == 3);
        const int b1 = __popcll(m0);
        const int b2 = b1 + __popcll(m1);
        const int b3 = b2 + __popcll(m2);
        const unsigned long long mq =
            (quart == 0) ? m0 : (quart == 1) ? m1 : (quart == 2) ? m2 : m3;
        const int bq =
            (quart == 0) ? 0 : (quart == 1) ? b1 : (quart == 2) ? b2 : b3;
        const unsigned long long below = (1ull << lane) - 1ull;
        const int pos = bq + __popcll(mq & below);

        if (hi)
            sortbuf[wave][qi][pos] = ((unsigned)iv << 16) | (hb & 0xFFFFu);
    }
    // wave-local LDS RAW: same-wave ds ordering via lgkmcnt, no barrier.

    float accL[8], accH[8];
    #pragma unroll
    for (int qi = 0; qi < 8; ++qi) { accL[qi] = 0.0f; accH[qi] = 0.0f; }

    // ---- 4-phase paired consume: phase p ~= quartile p (2 MiB L2 slice).
    // One dword wave-instr gathers TWO full 128B rows: lo half -> entry
    // e=8p+2t, hi half -> e+1. pk sourced per-half from LDS (broadcast
    // read, 2 addrs/wave -> conflict-free); all address math per-lane VGPR.
    #pragma unroll
    for (int p = 0; p < 4; ++p) {
        #pragma unroll
        for (int qi = 0; qi < 8; ++qi) {
            #pragma unroll
            for (int t = 0; t < 4; ++t) {
                const unsigned pk = sortbuf[wave][qi][p * 8 + 2 * t + h];
                __half_raw hw; hw.x = (unsigned short)(pk & 0xFFFFu);
                const float w = __half2float(__half(hw));
                const unsigned off = ((pk >> 16) << 7) + lanebyte;
                const unsigned u = *(const unsigned*)((const char*)a16 + off);
                union { unsigned u32; __half2 h2; } cv;
                cv.u32 = u;
                const float2 f2 = __half22float2(cv.h2);
                accL[qi] = fmaf(w, f2.x, accL[qi]);
                accH[qi] = fmaf(w, f2.y, accH[qi]);
            }
        }
    }

    // ---- cross-half reduce + transposed tile write (lo half writes) ----
    #pragma unroll
    for (int qi = 0; qi < 8; ++qi) {
        const float sL = accL[qi] + __shfl_xor(accL[qi], 32);
        const float sH = accH[qi] + __shfl_xor(accH[qi], 32);
        if (!hi) {
            tile[wave * 8 + qi][2 * lane31]     = sL;
            tile[wave * 8 + qi][2 * lane31 + 1] = sH;
        }
    }

    __syncthreads();

    // coalesced [F, N] store: each wave writes 8 channel-rows of 64 floats
    #pragma unroll
    for (int fi = 0; fi < 8; ++fi) {
        const int f = wave * 8 + fi;
        __builtin_nontemporal_store(tile[lane][f],
                                    &out[(size_t)f * N_Q + n0 + lane]);
    }
}

// ---- fallback: pure fp32 (no workspace) ----
__global__ __launch_bounds__(256) void knn_exp_f32(
    const float* __restrict__ dmat,
    const int*   __restrict__ imat,
    const float* __restrict__ alpha,
    const float* __restrict__ sigma,
    float*       __restrict__ out)
{
    __shared__ float tile[64][65];
    const int lane = threadIdx.x & 63;
    const int wave = threadIdx.x >> 6;
    const int n0   = blockIdx.x * 64;
    const float s = sigma[0];
    const float c = -0.5f / (s * s);

    for (int qi = 0; qi < 16; ++qi) {
        const int q = wave * 16 + qi;
        const int n = n0 + q;
        float wv = 0.0f;
        int   iv = 0;
        if (lane < 32) {
            wv = __expf(c * dmat[(size_t)n * K_NB + lane]);
        } else {
            iv = imat[(size_t)n * K_NB + (lane - 32)];
        }
        float acc = 0.0f;
        #pragma unroll
        for (int k = 0; k < K_NB; ++k) {
            const float wk = __int_as_float(
                __builtin_amdgcn_readlane(__float_as_int(wv), k));
            const int   ik = __builtin_amdgcn_readlane(iv, 32 + k);
            acc = fmaf(wk, alpha[(size_t)ik * F_CH + lane], acc);
        }
        tile[q][lane] = acc;
    }
    __syncthreads();
    #pragma unroll
    for (int fi = 0; fi < 16; ++fi) {
        const int f = wave * 16 + fi;
        out[(size_t)f * N_Q + n0 + lane] = tile[lane][f];
    }
}

extern "C" void kernel_launch(void* const* d_in, const int* in_sizes, int n_in,
                              void* d_out, int out_size, void* d_ws, size_t ws_size,
                              hipStream_t stream) {
    const float* dmat  = (const float*)d_in[0];
    const int*   imat  = (const int*)d_in[1];
    const float* alpha = (const float*)d_in[2];
    const float* sigma = (const float*)d_in[3];
    float* out = (float*)d_out;

    const size_t bytes_a16 = (size_t)M_ROWS * F_CH * sizeof(__half);  // 8 MiB

    if (ws_size >= bytes_a16) {
        __half* a16 = (__half*)d_ws;
        hipLaunchKernelGGL(cvt_alpha_f16, dim3(M_ROWS * F_CH / 8 / 256),
                           dim3(256), 0, stream, alpha, a16);
        hipLaunchKernelGGL(knn_exp_pair, dim3(N_Q / 64), dim3(512), 0,
                           stream, dmat, imat, a16, sigma, out);
    } else {
        hipLaunchKernelGGL(knn_exp_f32, dim3(N_Q / 64), dim3(256), 0, stream,
                           dmat, imat, alpha, sigma, out);
    }
}

// Round 13
// 58.893 us; speedup vs baseline: 4.2204x; 4.2204x over previous
//
#include <hip/hip_runtime.h>
#include <hip/hip_fp16.h>

// KnnExpansion: out[f, n] = sum_k alpha[i[n,k], f] * exp(-0.5 * d[n,k] / sigma^2)
// N=131072, K=32, M=65536, F=64.
//
// Model (r1-r12): consume is bound by L2-line REQUEST count (r11's junk
// scale-gathers explain its regression quantitatively: 760 vs 512 req/wave
// = 1.48x ~ measured 1.43x). This round: per-GLOBAL-scale int8 table ->
// 64B rows = ONE line per gather (vs f16's two), scale folded into the f16
// packed weight at prologue time (zero extra gathers, zero scalar loads).
// Consume keeps r10's proven shape: readlane -> SGPR row base, sbyte load,
// cvt, fma. Global absmax computed in 2 cheap streaming pre-passes.
// Expected absmax ~0.3 < 0.4875 (r11 measured 0.156 at half the step).

#define N_Q    131072
#define K_NB   32
#define F_CH   64
#define M_ROWS 65536
#define ABS_BLOCKS 1024   // 1024 blk x 256 thr x 16 elems = 4,194,304

// ---- pass 1: per-block absmax partials over alpha ----
__global__ __launch_bounds__(256) void absmax_pass(
    const float* __restrict__ alpha, float* __restrict__ partial)
{
    const int t = blockIdx.x * 256 + threadIdx.x;
    const float4* a4 = (const float4*)alpha + (size_t)t * 4;
    float m = 0.0f;
    #pragma unroll
    for (int j = 0; j < 4; ++j) {
        const float4 v = a4[j];
        m = fmaxf(m, fmaxf(fmaxf(fabsf(v.x), fabsf(v.y)),
                           fmaxf(fabsf(v.z), fabsf(v.w))));
    }
    #pragma unroll
    for (int off = 32; off; off >>= 1) m = fmaxf(m, __shfl_xor(m, off));

    __shared__ float wred[4];
    const int lane = threadIdx.x & 63, wave = threadIdx.x >> 6;
    if (lane == 0) wred[wave] = m;
    __syncthreads();
    if (threadIdx.x == 0)
        partial[blockIdx.x] =
            fmaxf(fmaxf(wred[0], wred[1]), fmaxf(wred[2], wred[3]));
}

// ---- pass 2: reduce partials (redundant per block, L2-hot) + quantize ----
__global__ __launch_bounds__(256) void quant_global(
    const float* __restrict__ alpha, const float* __restrict__ partial,
    signed char* __restrict__ a8, float* __restrict__ scale_out)
{
    __shared__ float sred[4];
    __shared__ float s_max;

    float m = fmaxf(fmaxf(partial[threadIdx.x],       partial[threadIdx.x + 256]),
                    fmaxf(partial[threadIdx.x + 512], partial[threadIdx.x + 768]));
    #pragma unroll
    for (int off = 32; off; off >>= 1) m = fmaxf(m, __shfl_xor(m, off));
    const int lane = threadIdx.x & 63, wave = threadIdx.x >> 6;
    if (lane == 0) sred[wave] = m;
    __syncthreads();
    if (threadIdx.x == 0) {
        float gm = fmaxf(fmaxf(sred[0], sred[1]), fmaxf(sred[2], sred[3]));
        if (!(gm > 0.0f)) gm = 1.0f;
        s_max = gm;
        if (blockIdx.x == 0) scale_out[0] = gm * (1.0f / 127.0f);
    }
    __syncthreads();
    const float inv = 127.0f / s_max;

    const int t = blockIdx.x * 256 + threadIdx.x;
    const float4* a4 = (const float4*)alpha + (size_t)t * 4;
    union { signed char q[16]; uint4 u; } pk;
    #pragma unroll
    for (int j = 0; j < 4; ++j) {
        const float4 v = a4[j];
        pk.q[j * 4 + 0] = (signed char)(int)rintf(v.x * inv);
        pk.q[j * 4 + 1] = (signed char)(int)rintf(v.y * inv);
        pk.q[j * 4 + 2] = (signed char)(int)rintf(v.z * inv);
        pk.q[j * 4 + 3] = (signed char)(int)rintf(v.w * inv);
    }
    *(uint4*)(&a8[(size_t)t * 16]) = pk.u;
}

// ---- fused main: r10 structure, int8 gather (1 line/row), folded scale ----
__global__ __launch_bounds__(512) void knn_exp_i8g(
    const float*       __restrict__ dmat,    // [N, 32]
    const int*         __restrict__ imat,    // [N, 32]
    const signed char* __restrict__ a8,      // [65536, 64]
    const float*       __restrict__ gscale,  // [1] = absmax/127
    const float*       __restrict__ sigma,   // [1]
    float*             __restrict__ out)     // [64, N]
{
    __shared__ float    tile[64][65];        // +1 pad
    __shared__ unsigned sortbuf[8][8][32];   // wave-local sort scratch

    const int lane = threadIdx.x & 63;
    const int wave = threadIdx.x >> 6;       // 8 waves x 8 queries
    const int n0   = blockIdx.x * 64;
    const bool hi  = (lane >= 32);

    const float s  = sigma[0];
    const float c  = -0.5f / (s * s);
    const float gs = gscale[0];              // uniform -> s_load

    // ---- batched prologue: 8 stream loads issued back-to-back (r10) ----
    const int nbase = n0 + wave * 8;
    const char* pbase = hi
        ? (const char*)&imat[(size_t)nbase * K_NB + (lane - 32)]
        : (const char*)&dmat[(size_t)nbase * K_NB + lane];
    unsigned raw[8];
    #pragma unroll
    for (int qi = 0; qi < 8; ++qi)
        raw[qi] = __builtin_nontemporal_load(
            (const unsigned*)(pbase + (size_t)qi * (K_NB * 4)));

    __builtin_amdgcn_sched_barrier(0);   // keep the batch; no sinking

    // ---- in-register quartile partition, pack (idx<<16 | f16(w*gs)) ----
    #pragma unroll
    for (int qi = 0; qi < 8; ++qi) {
        const float wv = __expf(c * __uint_as_float(raw[qi])); // valid on lo
        const int   iv = (int)raw[qi];                         // valid on hi

        // fold the global int8 scale into the weight before f16 pack
        const unsigned hbits = (unsigned)__half_as_ushort(
            __float2half_rn(wv * gs));
        const unsigned hb = (unsigned)__shfl((int)hbits, lane & 31);

        const int quart = (iv >> 14) & 3;
        const unsigned long long m0 = __ballot(hi && quart == 0);
        const unsigned long long m1 = __ballot(hi && quart == 1);
        const unsigned long long m2 = __ballot(hi && quart == 2);
        const unsigned long long m3 = __ballot(hi && quart == 3);
        const int b1 = __popcll(m0);
        const int b2 = b1 + __popcll(m1);
        const int b3 = b2 + __popcll(m2);
        const unsigned long long mq =
            (quart == 0) ? m0 : (quart == 1) ? m1 : (quart == 2) ? m2 : m3;
        const int bq =
            (quart == 0) ? 0 : (quart == 1) ? b1 : (quart == 2) ? b2 : b3;
        const unsigned long long below = (1ull << lane) - 1ull;
        const int pos = bq + __popcll(mq & below);

        if (hi)
            sortbuf[wave][qi][pos] = ((unsigned)iv << 16) | (hb & 0xFFFFu);
    }

    // wave-local RAW through LDS (lgkmcnt-ordered, no barrier needed)
    unsigned pv[8];
    float    acc[8];
    #pragma unroll
    for (int qi = 0; qi < 8; ++qi) {
        pv[qi]  = sortbuf[wave][qi][lane & 31];
        acc[qi] = 0.0f;
    }

    // ---- 4-phase consume: phase p ~= quartile p (1 MiB L2 slice).
    // ONE 64B line per row; weight already carries the global scale.
    #pragma unroll
    for (int p = 0; p < 4; ++p) {
        #pragma unroll
        for (int qi = 0; qi < 8; ++qi) {
            #pragma unroll
            for (int j = 0; j < 8; ++j) {
                const unsigned pk = (unsigned)__builtin_amdgcn_readlane(
                    (int)pv[qi], p * 8 + j);              // SGPR
                __half_raw hr; hr.x = (unsigned short)(pk & 0xFFFFu);
                const float w = __half2float(__half(hr));
                const unsigned off = ((pk >> 16) << 6) + (unsigned)lane;
                const signed char q = a8[off];
                acc[qi] = fmaf(w, (float)q, acc[qi]);
            }
        }
    }

    #pragma unroll
    for (int qi = 0; qi < 8; ++qi)
        tile[wave * 8 + qi][lane] = acc[qi];

    __syncthreads();

    // coalesced [F, N] store: each wave writes 8 channel-rows of 64 floats
    #pragma unroll
    for (int fi = 0; fi < 8; ++fi) {
        const int f = wave * 8 + fi;
        __builtin_nontemporal_store(tile[lane][f],
                                    &out[(size_t)f * N_Q + n0 + lane]);
    }
}

// ---- fallback: pure fp32 (no workspace) ----
__global__ __launch_bounds__(256) void knn_exp_f32(
    const float* __restrict__ dmat,
    const int*   __restrict__ imat,
    const float* __restrict__ alpha,
    const float* __restrict__ sigma,
    float*       __restrict__ out)
{
    __shared__ float tile[64][65];
    const int lane = threadIdx.x & 63;
    const int wave = threadIdx.x >> 6;
    const int n0   = blockIdx.x * 64;
    const float s = sigma[0];
    const float c = -0.5f / (s * s);

    for (int qi = 0; qi < 16; ++qi) {
        const int q = wave * 16 + qi;
        const int n = n0 + q;
        float wv = 0.0f;
        int   iv = 0;
        if (lane < 32) {
            wv = __expf(c * dmat[(size_t)n * K_NB + lane]);
        } else {
            iv = imat[(size_t)n * K_NB + (lane - 32)];
        }
        float acc = 0.0f;
        #pragma unroll
        for (int k = 0; k < K_NB; ++k) {
            const float wk = __int_as_float(
                __builtin_amdgcn_readlane(__float_as_int(wv), k));
            const int   ik = __builtin_amdgcn_readlane(iv, 32 + k);
            acc = fmaf(wk, alpha[(size_t)ik * F_CH + lane], acc);
        }
        tile[q][lane] = acc;
    }
    __syncthreads();
    #pragma unroll
    for (int fi = 0; fi < 16; ++fi) {
        const int f = wave * 16 + fi;
        out[(size_t)f * N_Q + n0 + lane] = tile[lane][f];
    }
}

extern "C" void kernel_launch(void* const* d_in, const int* in_sizes, int n_in,
                              void* d_out, int out_size, void* d_ws, size_t ws_size,
                              hipStream_t stream) {
    const float* dmat  = (const float*)d_in[0];
    const int*   imat  = (const int*)d_in[1];
    const float* alpha = (const float*)d_in[2];
    const float* sigma = (const float*)d_in[3];
    float* out = (float*)d_out;

    const size_t bytes_a8      = (size_t)M_ROWS * F_CH;             // 4 MiB
    const size_t bytes_partial = (size_t)ABS_BLOCKS * sizeof(float);
    const size_t need = bytes_a8 + bytes_partial + sizeof(float);

    if (ws_size >= need) {
        signed char* a8      = (signed char*)d_ws;
        float*       partial = (float*)((char*)d_ws + bytes_a8);
        float*       scl     = (float*)((char*)d_ws + bytes_a8 + bytes_partial);
        hipLaunchKernelGGL(absmax_pass, dim3(ABS_BLOCKS), dim3(256), 0, stream,
                           alpha, partial);
        hipLaunchKernelGGL(quant_global, dim3(ABS_BLOCKS), dim3(256), 0, stream,
                           alpha, partial, a8, scl);
        hipLaunchKernelGGL(knn_exp_i8g, dim3(N_Q / 64), dim3(512), 0, stream,
                           dmat, imat, a8, scl, sigma, out);
    } else {
        hipLaunchKernelGGL(knn_exp_f32, dim3(N_Q / 64), dim3(256), 0, stream,
                           dmat, imat, alpha, sigma, out);
    }
}